// Round 4
// baseline (292.272 us; speedup 1.0000x reference)
//
#include <hip/hip_runtime.h>
#include <hip/hip_bf16.h>

#define TEMP_INV 20.0f
#define BATCH    1024
#define NSAMP    100000
#define NFEAT    256
#define BK       64
#define NCH2     391                 /* 391*256 = 100096 = padded fb rows */

typedef __bf16 bf16x8 __attribute__((ext_vector_type(8)));
typedef float  f32x4  __attribute__((ext_vector_type(4)));

// async global->LDS, 16B per lane; LDS dest = wave-uniform base + lane*16
#define GLOAD_LDS16(g, l) __builtin_amdgcn_global_load_lds(               \
    (const __attribute__((address_space(1))) void*)(g),                   \
    (__attribute__((address_space(3))) void*)(l), 16, 0, 0)

#define WAITV(N) asm volatile("s_waitcnt vmcnt(" #N ")" ::: "memory")

// ---------------------------------------------------------------------------
// Kernel 0: convert feats (+zero-pad to 100096 rows) and inputs to bf16.
// ---------------------------------------------------------------------------
__global__ __launch_bounds__(256) void convert_kernel(
    const float* __restrict__ feats, const float* __restrict__ inputs,
    __bf16* __restrict__ fb, __bf16* __restrict__ ib, float* __restrict__ out)
{
    if (blockIdx.x == 0 && threadIdx.x == 0) out[0] = 0.0f;
    int b = blockIdx.x;
    if (b < 3125) {
        size_t u0 = (size_t)b * 1024 + threadIdx.x;
        #pragma unroll
        for (int i = 0; i < 4; i++) {
            size_t u = u0 + (size_t)i * 256;
            const float4* src = (const float4*)(feats + u * 8);
            float4 a = src[0], c = src[1];
            bf16x8 o;
            o[0] = (__bf16)a.x; o[1] = (__bf16)a.y; o[2] = (__bf16)a.z; o[3] = (__bf16)a.w;
            o[4] = (__bf16)c.x; o[5] = (__bf16)c.y; o[6] = (__bf16)c.z; o[7] = (__bf16)c.w;
            *(bf16x8*)(fb + u * 8) = o;
        }
    } else if (b < 3128) {
        size_t u0 = 3200000 + (size_t)(b - 3125) * 1024 + threadIdx.x;
        bf16x8 z;
        #pragma unroll
        for (int q = 0; q < 8; q++) z[q] = (__bf16)0.0f;
        #pragma unroll
        for (int i = 0; i < 4; i++) {
            size_t u = u0 + (size_t)i * 256;
            if (u < 3203072) *(bf16x8*)(fb + u * 8) = z;
        }
    } else {
        size_t u0 = (size_t)(b - 3128) * 1024 + threadIdx.x;
        #pragma unroll
        for (int i = 0; i < 4; i++) {
            size_t u = u0 + (size_t)i * 256;
            const float4* src = (const float4*)(inputs + u * 8);
            float4 a = src[0], c = src[1];
            bf16x8 o;
            o[0] = (__bf16)a.x; o[1] = (__bf16)a.y; o[2] = (__bf16)a.z; o[3] = (__bf16)a.w;
            o[4] = (__bf16)c.x; o[5] = (__bf16)c.y; o[6] = (__bf16)c.z; o[7] = (__bf16)c.w;
            *(bf16x8*)(ib + u * 8) = o;
        }
    }
}

// ---------------------------------------------------------------------------
// Kernel 1: per-row target logit + per-row softmax shift m=5.4*||x||.
// ---------------------------------------------------------------------------
__global__ __launch_bounds__(256) void target_kernel(
    const float* __restrict__ inputs, const int* __restrict__ targets,
    const float* __restrict__ feats, float* __restrict__ tlogit,
    float* __restrict__ mrow)
{
    int lane = threadIdx.x & 63;
    int wid  = threadIdx.x >> 6;
    int row  = blockIdx.x * 4 + wid;
    int tgt  = targets[row];
    const float4* a = (const float4*)(inputs + (size_t)row * NFEAT);
    const float4* f = (const float4*)(feats  + (size_t)tgt * NFEAT);
    float4 av = a[lane];
    float4 fv = f[lane];
    float d  = av.x * fv.x + av.y * fv.y + av.z * fv.z + av.w * fv.w;
    float n2 = av.x * av.x + av.y * av.y + av.z * av.z + av.w * av.w;
    #pragma unroll
    for (int off = 1; off < 64; off <<= 1) {
        d  += __shfl_xor(d, off, 64);
        n2 += __shfl_xor(n2, off, 64);
    }
    if (lane == 0) {
        tlogit[row] = d * TEMP_INV;
        mrow[row]   = 5.4f * sqrtf(n2);
    }
}

// ---------------------------------------------------------------------------
// Kernel 2: 8-phase counted-vmcnt 256x256 MFMA GEMM + exp-sum epilogue.
// 512 thr = 8 waves (2wm x 4wn), wave-tile 128x64, acc[8][4], BK=64,
// K=256 -> 2 iterations x 8 phases.  2-slot LDS ring (even tiles slot0,
// odd slot1); per phase: ds_read one C-quadrant (mh,nh) + stage half-tiles
// whose previous-tile region is provably dead; vmcnt(4) at phases 4/8 only.
// Ring schedule (derived; overwrite-safety + wait-coverage checked per-half):
//   ph1: stage A-h0,B-h1 of own odd tile (always)
//   ph3: A-h0(next even)   ph4: B-h0(next even) + W1
//   ph5: A-h1,B-h1(next even)  ph7: A-h1(next odd)  ph8: B-h0(next odd) + W2
// Quadrant read order: even tile (0,0),(0,1),(1,0),(1,1); odd (1,0),(1,1),(0,0),(0,1).
// ---------------------------------------------------------------------------
__global__ __launch_bounds__(512, 2) void gemm_softmax_kernel(
    const __bf16* __restrict__ A, const __bf16* __restrict__ B,
    const float* __restrict__ mrow, float* __restrict__ partials)
{
    int g  = blockIdx.x;            // 4 mx x 391 ny; mx fastest (B-chunk share)
    int mx = g & 3;
    int ny = g >> 2;
    int m0 = mx * 256;
    int n0 = ny * 256;

    __shared__ __bf16 Abuf[2][256][BK];   // 64 KB
    __shared__ __bf16 Bbuf[2][256][BK];   // 64 KB

    const int tid    = threadIdx.x;
    const int lane   = tid & 63;
    const int wid    = tid >> 6;          // 0..7
    const int wm     = wid & 1;
    const int wn     = wid >> 1;          // 0..3
    const int lrow   = lane & 15;
    const int quad   = lane >> 4;
    const int rowoff = lane >> 3;         // 0..7
    const int kc     = (lane & 7) ^ rowoff;   // pre-swizzled k-chunk
    const int bgrp   = wid >> 2;          // B staging: 0/1

    const __bf16* Ag = A + (size_t)(m0 + wid * 8 + rowoff) * NFEAT + kc * 8;
    const __bf16* Bg = B + (size_t)(n0 + (wid & 3) * 8 + rowoff) * NFEAT + kc * 8;

    f32x4 acc[8][4] = {};

// stage A-half H (128 rows: [H*64,+64) u [128+H*64,+64)) of K-tile KT -> slot
#define STG_A(SLOT, KT, H) do {                                               \
    GLOAD_LDS16(Ag + (size_t)((H) * 64) * NFEAT + (KT) * BK,                  \
                &Abuf[SLOT][(H) * 64 + wid * 8][0]);                          \
    GLOAD_LDS16(Ag + (size_t)(128 + (H) * 64) * NFEAT + (KT) * BK,            \
                &Abuf[SLOT][128 + (H) * 64 + wid * 8][0]);                    \
  } while (0)
// stage B-half H (rows {q*64 + H*32 .. +32} for q=0..3) of K-tile KT -> slot
#define STG_B(SLOT, KT, H) do {                                               \
    GLOAD_LDS16(Bg + (size_t)(bgrp * 64 + (H) * 32) * NFEAT + (KT) * BK,      \
                &Bbuf[SLOT][bgrp * 64 + (H) * 32 + (wid & 3) * 8][0]);        \
    GLOAD_LDS16(Bg + (size_t)(128 + bgrp * 64 + (H) * 32) * NFEAT + (KT) * BK,\
                &Bbuf[SLOT][128 + bgrp * 64 + (H) * 32 + (wid & 3) * 8][0]);  \
  } while (0)

#define PHASE(SLOT, MH, NH, STAGES, WAITS) do {                               \
    bf16x8 af[4][2], bfr[2][2];                                               \
    _Pragma("unroll")                                                         \
    for (int ks2 = 0; ks2 < 2; ks2++) {                                       \
      _Pragma("unroll")                                                       \
      for (int mf = 0; mf < 4; mf++) {                                        \
        int R = wm * 128 + ((MH) * 4 + mf) * 16 + lrow;                       \
        af[mf][ks2] = *(const bf16x8*)&Abuf[SLOT][R][((ks2*4+quad)^(R&7))*8]; \
      }                                                                       \
      _Pragma("unroll")                                                       \
      for (int j = 0; j < 2; j++) {                                           \
        int R = wn * 64 + ((NH) * 2 + j) * 16 + lrow;                         \
        bfr[j][ks2] = *(const bf16x8*)&Bbuf[SLOT][R][((ks2*4+quad)^(R&7))*8]; \
      }                                                                       \
    }                                                                         \
    STAGES;                                                                   \
    WAITS;                                                                    \
    __builtin_amdgcn_s_barrier();                                             \
    __builtin_amdgcn_s_setprio(1);                                            \
    _Pragma("unroll")                                                         \
    for (int ks2 = 0; ks2 < 2; ks2++)                                         \
      _Pragma("unroll")                                                       \
      for (int mf = 0; mf < 4; mf++)                                          \
        _Pragma("unroll")                                                     \
        for (int j = 0; j < 2; j++)                                           \
          acc[(MH)*4+mf][(NH)*2+j] = __builtin_amdgcn_mfma_f32_16x16x32_bf16( \
              af[mf][ks2], bfr[j][ks2], acc[(MH)*4+mf][(NH)*2+j], 0, 0, 0);   \
    __builtin_amdgcn_s_setprio(0);                                            \
    __builtin_amdgcn_s_barrier();                                             \
  } while (0)

    // ---- prologue: tile0 fully + tile1 {A-h1, B-h0}; drain once ----
    STG_A(0, 0, 0); STG_A(0, 0, 1); STG_B(0, 0, 0); STG_B(0, 0, 1);
    STG_A(1, 1, 1); STG_B(1, 1, 0);
    asm volatile("s_waitcnt vmcnt(0)" ::: "memory");
    __builtin_amdgcn_s_barrier();
    __builtin_amdgcn_sched_barrier(0);

    #pragma unroll
    for (int i = 0; i < 2; i++) {
        const int kt0 = 2 * i, kt1 = 2 * i + 1;
        // ph1: even(0,0); stage own odd tile's A-h0 + B-h1 (always)
        PHASE(0, 0, 0, { STG_A(1, kt1, 0); STG_B(1, kt1, 1); }, {});
        // ph2: even(0,1)
        PHASE(0, 0, 1, {}, {});
        // ph3: even(1,0); stage next-even A-h0 (A-h0 even dead after ph2)
        PHASE(0, 1, 0, { if (i == 0) STG_A(0, kt0 + 2, 0); }, {});
        // ph4: even(1,1); stage next-even B-h0; W1
        PHASE(0, 1, 1, { if (i == 0) STG_B(0, kt0 + 2, 0); },
              { if (i == 0) { WAITV(4); } else { WAITV(0); }
                __builtin_amdgcn_sched_barrier(0); });
        // ph5: odd(1,0); stage next-even A-h1 + B-h1
        PHASE(1, 1, 0, { if (i == 0) { STG_A(0, kt0 + 2, 1); STG_B(0, kt0 + 2, 1); } }, {});
        // ph6: odd(1,1)
        PHASE(1, 1, 1, {}, {});
        // ph7: odd(0,0); stage next-odd A-h1 (A-h1 odd dead after ph6)
        PHASE(1, 0, 0, { if (i == 0) STG_A(1, kt1 + 2, 1); }, {});
        // ph8: odd(0,1); stage next-odd B-h0; W2
        PHASE(1, 0, 1, { if (i == 0) STG_B(1, kt1 + 2, 0); },
              { if (i == 0) { WAITV(4); __builtin_amdgcn_sched_barrier(0); } });
    }

#undef PHASE
#undef STG_A
#undef STG_B

    // ---- epilogue: s = sum_cols exp(20*acc - m_row) ----
    // C layout per 16x16 tile: row = quad*4 + reg, col = lane&15
    __syncthreads();
    float* redf = (float*)&Abuf[0][0][0];   // reuse LDS: red[4][256]
    #pragma unroll
    for (int mf = 0; mf < 8; mf++) {
        #pragma unroll
        for (int reg = 0; reg < 4; reg++) {
            float mrv = mrow[m0 + wm * 128 + mf * 16 + quad * 4 + reg];
            float s = 0.0f;
            #pragma unroll
            for (int nf = 0; nf < 4; nf++)
                s += __expf(acc[mf][nf][reg] * TEMP_INV - mrv);
            #pragma unroll
            for (int off = 1; off < 16; off <<= 1)
                s += __shfl_xor(s, off, 64);
            if (lrow == 0)
                redf[wn * 256 + wm * 128 + mf * 16 + quad * 4 + reg] = s;
        }
    }
    __syncthreads();
    if (tid < 256)
        partials[(size_t)ny * BATCH + (m0 + tid)] =
            redf[tid] + redf[256 + tid] + redf[512 + tid] + redf[768 + tid];
}

// ---------------------------------------------------------------------------
// Kernel 3: sum partials -> lse = m_row + log(S) -> nll -> mean (atomicAdd).
// ---------------------------------------------------------------------------
__global__ __launch_bounds__(256) void reduce_kernel(
    const float* __restrict__ partials, const float* __restrict__ tlogit,
    const float* __restrict__ mrow, float* __restrict__ out)
{
    __shared__ float red2[8][32];
    int tid = threadIdx.x;
    int rl  = tid & 31;
    int sp  = tid >> 5;
    int row = blockIdx.x * 32 + rl;
    int cs  = sp * 49;
    int ce  = cs + 49 < NCH2 ? cs + 49 : NCH2;
    float s = 0.f;
    #pragma unroll 4
    for (int c = cs; c < ce; c++)
        s += partials[(size_t)c * BATCH + row];
    red2[sp][rl] = s;
    __syncthreads();
    if (tid < 32) {
        float S = 0.f;
        #pragma unroll
        for (int q = 0; q < 8; q++) S += red2[q][rl];
        float nll = (mrow[row] + logf(S)) - tlogit[row];
        #pragma unroll
        for (int off = 1; off < 32; off <<= 1)
            nll += __shfl_xor(nll, off, 64);
        if (rl == 0) atomicAdd(out, nll * (1.0f / BATCH));
    }
}

// ---------------------------------------------------------------------------
extern "C" void kernel_launch(void* const* d_in, const int* in_sizes, int n_in,
                              void* d_out, int out_size, void* d_ws, size_t ws_size,
                              hipStream_t stream) {
    const float* inputs  = (const float*)d_in[0];
    const int*   targets = (const int*)d_in[1];
    const float* feats   = (const float*)d_in[2];
    float* out = (float*)d_out;

    // ws layout (bytes):
    //   fb       : 0          .. 51,249,152   (100096*256 bf16)
    //   ib       : 51,249,152 .. 51,773,440   (1024*256 bf16)
    //   partials : 51,773,440 .. 53,375,424   (391*1024 f32)
    //   tlogit   : 54,976,512 .. +4096
    //   mrow     : 54,980,608 .. +4096
    __bf16* fb       = (__bf16*)d_ws;
    __bf16* ib       = (__bf16*)((char*)d_ws + 51249152);
    float*  partials = (float*)((char*)d_ws + 51773440);
    float*  tlogit   = (float*)((char*)d_ws + 54976512);
    float*  mrow     = (float*)((char*)d_ws + 54980608);

    convert_kernel<<<3160, 256, 0, stream>>>(feats, inputs, fb, ib, out);
    target_kernel<<<BATCH / 4, 256, 0, stream>>>(inputs, targets, feats, tlogit, mrow);
    gemm_softmax_kernel<<<4 * NCH2, 512, 0, stream>>>(ib, fb, mrow, partials);
    reduce_kernel<<<BATCH / 32, 256, 0, stream>>>(partials, tlogit, mrow, out);
}